// Round 15
// baseline (398.556 us; speedup 1.0000x reference)
//
#include <hip/hip_runtime.h>
#include <cstdint>
#include <cstddef>

#define NROWS 262144
#define EMB 256
#define NB 512
#define NCOPY 8
#define T_TILES 8
#define SLOPE 0.01f

typedef __attribute__((ext_vector_type(8))) short short8;
typedef __attribute__((ext_vector_type(4))) float f32x4;

__device__ __forceinline__ unsigned short f2bf(float f) {
    unsigned u = __float_as_uint(f);
    u += 0x7FFFu + ((u >> 16) & 1u);
    return (unsigned short)(u >> 16);
}

__device__ __forceinline__ short8 pack8(const float4& lo, const float4& hi) {
    short8 s;
    s[0] = (short)f2bf(lo.x); s[1] = (short)f2bf(lo.y);
    s[2] = (short)f2bf(lo.z); s[3] = (short)f2bf(lo.w);
    s[4] = (short)f2bf(hi.x); s[5] = (short)f2bf(hi.y);
    s[6] = (short)f2bf(hi.z); s[7] = (short)f2bf(hi.w);
    return s;
}

// async 16B global -> LDS (DMA, no VGPR round trip)
__device__ __forceinline__ void gld16f(float* l, const float* g) {
    __builtin_amdgcn_global_load_lds(
        (const __attribute__((address_space(1))) unsigned int*)g,
        (__attribute__((address_space(3))) unsigned int*)l, 16, 0, 0);
}
__device__ __forceinline__ void gld16u(unsigned short* l, const unsigned short* g) {
    __builtin_amdgcn_global_load_lds(
        (const __attribute__((address_space(1))) unsigned int*)g,
        (__attribute__((address_space(3))) unsigned int*)l, 16, 0, 0);
}

// ---------- prep (merged init): transpose W_feat + zero partial buffers ----------
__global__ __launch_bounds__(256) void k_prep(const float* __restrict__ Wf,
                                              unsigned short* __restrict__ Wt2,
                                              float4* __restrict__ xgPart4,
                                              float4* __restrict__ dPart4) {
    const int b = blockIdx.x, t = threadIdx.x;
    if (b < 256) {
        // W_feat[k=b][col=t] -> Wt2[k>>3][col][k&7]  (chunked: staging reads contiguous)
        float v = Wf[(size_t)b * EMB + t];
        Wt2[((size_t)(b >> 3) << 11) + (t << 3) + (b & 7)] = f2bf(v);
    } else {
        const int i = (b - 256) * 256 + t;
        if (i < NCOPY * NB * EMB / 4) xgPart4[i] = (float4){0.f, 0.f, 0.f, 0.f};
        else dPart4[i - NCOPY * NB * EMB / 4] = (float4){0.f, 0.f, 0.f, 0.f};
    }
}

// stage A K-step (64 rows x 32 k f32, row-chunk XOR swizzled source, linear LDS):
// 1 DMA per thread for t<512; waves 8..15 don't stage (their vmcnt waits are trivial).
#define STAGE_A(B, KT) do {                                                       \
    if (t < 512) {                                                                \
        const int row_ = t >> 3, c_ = t & 7;                                      \
        const int cs_ = c_ ^ (row_ & 7);                                          \
        gld16f(&xbuf[B][t * 4], x + ((r0 + row_) << 8) + (KT) + (cs_ << 2));      \
    }                                                                             \
} while (0)

// ---------- fused: gate + exp + bf16 MFMA feat GEMM + weighted segment reduce ----------
// 1024 threads = 16 waves (wr = w&3: 16-row group, wcg = w>>2: 64-col group).
// B (128 KB bf16, chunked) RESIDENT in LDS -- staged once per block, zero B barriers.
// Each block processes T_TILES=8 consecutive 64-row tiles; per tile the validated
// 2-barrier double-buffered A pipeline (counted vmcnt). Staged volume: 332 MB total.
__global__ __launch_bounds__(1024, 4) void k_fused(const float* __restrict__ x,
                                                   const unsigned short* __restrict__ Wt2,
                                                   const float* __restrict__ wm,
                                                   const float* __restrict__ bfeat,
                                                   const int* __restrict__ bind,
                                                   float* __restrict__ dPart,
                                                   float* __restrict__ xgPart) {
    __shared__ unsigned short bbuf[32 * 2048];   // 128 KB resident B [k>>3][col][k&7]
    __shared__ float          xbuf[2][64 * 32];  // A: 2 x 8 KB
    __shared__ float wm_s[256];
    __shared__ float w_s[64];
    __shared__ float pxg[2][256];
    __shared__ float pden[2];
    __shared__ int   seg_s[64];
    __shared__ int   segid_s[4];
    __shared__ int   uni_s[4];

    const int t    = threadIdx.x;
    const int lane = t & 63;
    const int w    = t >> 6;
    const int wr   = w & 3;        // 16-row group 0..3
    const int wcg  = w >> 2;       // 64-col group 0..3
    const int fr   = lane & 15;
    const int fg   = lane >> 4;
    const int cp   = blockIdx.x & (NCOPY - 1);

    // ---- block prologue: stage full B (contiguous 128 KB DMA) + wm_s ----
#pragma unroll
    for (int q = 0; q < 8; q++) {
        const int i = q * 1024 + t;
        const int slab = i >> 8, off = i & 255;
        gld16u(&bbuf[slab * 2048 + off * 8], Wt2 + ((size_t)slab << 11) + off * 8);
    }
    if (t < 256) wm_s[t] = wm[t];

    for (int tt = 0; tt < T_TILES; tt++) {
        const size_t r0 = ((size_t)blockIdx.x * T_TILES + tt) * 64;
        if (tt > 0) __syncthreads();   // previous tile fully done (flush reads incl.)
        if (t < 64) seg_s[t] = bind[r0 + t];
        if (t < 256) { pxg[0][t] = 0.f; pxg[1][t] = 0.f; }
        if (t < 2)   pden[t] = 0.f;

        STAGE_A(0, 0);   // tile prologue: step 0 into buf 0

        f32x4 acc[4];
#pragma unroll
        for (int n = 0; n < 4; n++) acc[n] = (f32x4){0.f, 0.f, 0.f, 0.f};
        float gp = 0.f;

#pragma unroll
        for (int s = 0; s < 8; s++) {
            const int buf = s & 1;
            if (s < 7) STAGE_A(buf ^ 1, (s + 1) * 32);
            // counted wait: retire A(s); A(s+1) stays in flight. Tile 0 step 0
            // drains fully (B prologue must land for ALL waves incl. non-stagers).
            if (s == 0) {
                if (tt == 0) asm volatile("s_waitcnt vmcnt(0) lgkmcnt(0)" ::: "memory");
                else         asm volatile("s_waitcnt vmcnt(1) lgkmcnt(0)" ::: "memory");
            } else if (s < 7) {
                asm volatile("s_waitcnt vmcnt(1)" ::: "memory");
            } else {
                asm volatile("s_waitcnt vmcnt(0)" ::: "memory");
            }
            __builtin_amdgcn_sched_barrier(0);
            __builtin_amdgcn_s_barrier();     // step-s data landed for all waves
            __builtin_amdgcn_sched_barrier(0);

            // ---- compute step s: pure LDS ----
            const float* xb = &xbuf[buf][0];
            const float4 wa  = *reinterpret_cast<const float4*>(&wm_s[s * 32 + fg * 8]);
            const float4 wbv = *reinterpret_cast<const float4*>(&wm_s[s * 32 + fg * 8 + 4]);
            const int r  = wr * 16 + fr;
            const int sl = (fg * 2) ^ (r & 7);
            const float4 lo = *reinterpret_cast<const float4*>(&xb[r * 32 + sl * 4]);
            const float4 hi = *reinterpret_cast<const float4*>(&xb[r * 32 + (sl ^ 1) * 4]);
            gp += lo.x * wa.x + lo.y * wa.y + lo.z * wa.z + lo.w * wa.w
                + hi.x * wbv.x + hi.y * wbv.y + hi.z * wbv.z + hi.w * wbv.w;
            const short8 a = pack8(lo, hi);
#pragma unroll
            for (int n = 0; n < 4; n++) {
                const short8 b = *reinterpret_cast<const short8*>(
                    &bbuf[(s * 4 + fg) * 2048 + ((wcg * 64 + n * 16 + fr) << 3)]);
                acc[n] = __builtin_amdgcn_mfma_f32_16x16x32_bf16(a, b, acc[n], 0, 0, 0);
            }

            // release buf[s&1] for the overwrite at step s+1
            asm volatile("s_waitcnt lgkmcnt(0)" ::: "memory");
            __builtin_amdgcn_sched_barrier(0);
            __builtin_amdgcn_s_barrier();
            __builtin_amdgcn_sched_barrier(0);
        }

        // ---- gate -> e (4 wcg waves redundant; only wcg==0 writes) ----
        gp += __shfl_xor(gp, 16, 64);
        gp += __shfl_xor(gp, 32, 64);
        // exp(b_mask) cancels in the softmax -> dropped
        if (wcg == 0 && lane < 16) w_s[wr * 16 + lane] = expf(gp);
        if (t < 4) {
            int s0 = seg_s[t * 16], ok = 1;
#pragma unroll
            for (int i = 1; i < 16; i++) ok &= (seg_s[t * 16 + i] == s0);
            segid_s[t] = s0;
            uni_s[t]   = ok;
        }
        __syncthreads();

        const int sid0 = seg_s[0];
        const int sid1 = seg_s[63];

        // ---- denom partials (LDS slots, global fallback for >2-segment tiles) ----
        if (t < 4) {
            if (uni_s[t]) {
                float s = 0.f;
#pragma unroll
                for (int i = 0; i < 16; i++) s += w_s[t * 16 + i];
                const int sid = segid_s[t];
                if (sid == sid0)      atomicAdd(&pden[0], s);
                else if (sid == sid1) atomicAdd(&pden[1], s);
                else atomicAdd(&dPart[cp * NB + sid], s);
            } else {
                for (int i = 0; i < 16; i++) {
                    const int sd = seg_s[t * 16 + i];
                    const float e = w_s[t * 16 + i];
                    if (sd == sid0)      atomicAdd(&pden[0], e);
                    else if (sd == sid1) atomicAdd(&pden[1], e);
                    else atomicAdd(&dPart[cp * NB + sd], e);
                }
            }
        }

        // ---- epilogue: bias -> leaky -> *e -> segmented reduce -> LDS slots ----
        {
            const int uni  = uni_s[wr];
            const int sid  = segid_s[wr];
            const int rowb = wr * 16;
#pragma unroll
            for (int n = 0; n < 4; n++) {
                const int col = wcg * 64 + n * 16 + fr;
                const float bia = bfeat[col];
                float vr[4];
#pragma unroll
                for (int r2 = 0; r2 < 4; r2++) {
                    const int row = rowb + fg * 4 + r2;
                    float v = acc[n][r2] + bia;
                    v = (v >= 0.f) ? v : SLOPE * v;
                    vr[r2] = v * w_s[row];
                }
                if (uni) {
                    float s = vr[0] + vr[1] + vr[2] + vr[3];
                    s += __shfl_xor(s, 16, 64);
                    s += __shfl_xor(s, 32, 64);
                    if (fg == 0) {
                        if (sid == sid0)      atomicAdd(&pxg[0][col], s);
                        else if (sid == sid1) atomicAdd(&pxg[1][col], s);
                        else atomicAdd(&xgPart[((size_t)(cp * NB + sid) << 8) + col], s);
                    }
                } else {
#pragma unroll
                    for (int r2 = 0; r2 < 4; r2++) {
                        const int sd = seg_s[rowb + fg * 4 + r2];
                        if (sd == sid0)      atomicAdd(&pxg[0][col], vr[r2]);
                        else if (sd == sid1) atomicAdd(&pxg[1][col], vr[r2]);
                        else atomicAdd(&xgPart[((size_t)(cp * NB + sd) << 8) + col], vr[r2]);
                    }
                }
            }
        }
        __syncthreads();

        // ---- flush tile partials into XCD-striped copies ----
        if (t < 256) {
            atomicAdd(&xgPart[((size_t)(cp * NB + sid0) << 8) + t], pxg[0][t]);
        } else if (t < 512) {
            if (sid1 != sid0)
                atomicAdd(&xgPart[((size_t)(cp * NB + sid1) << 8) + (t - 256)], pxg[1][t - 256]);
        } else if (t == 512) {
            atomicAdd(&dPart[cp * NB + sid0], pden[0]);
        } else if (t == 513) {
            if (sid1 != sid0) atomicAdd(&dPart[cp * NB + sid1], pden[1]);
        }
    }
}

// ---------- out = leaky_relu([xg/denom, xg_prev] @ W_t + b_t) + xg_prev ----------
__global__ __launch_bounds__(256) void k_out(const float* __restrict__ xgPart,
                                             const float* __restrict__ dPart,
                                             const float* __restrict__ xgp,
                                             const float* __restrict__ Wtr,
                                             const float* __restrict__ bt,
                                             float* __restrict__ out) {
    __shared__ float h[8][512];
    const int c  = threadIdx.x;
    const int b0 = blockIdx.x * 8;
#pragma unroll
    for (int r = 0; r < 8; r++) {
        const int b = b0 + r;
        float den = 0.f, s = 0.f;
#pragma unroll
        for (int cpy = 0; cpy < NCOPY; cpy++) {
            den += dPart[cpy * NB + b];
            s   += xgPart[((size_t)(cpy * NB + b) << 8) + c];
        }
        h[r][c]       = s / fmaxf(den, 1e-16f);
        h[r][EMB + c] = xgp[(size_t)b * EMB + c];
    }
    __syncthreads();
    float acc[8] = {0.f, 0.f, 0.f, 0.f, 0.f, 0.f, 0.f, 0.f};
    for (int k = 0; k < 2 * EMB; k++) {
        float wv = Wtr[(size_t)k * EMB + c];
#pragma unroll
        for (int r = 0; r < 8; r++) acc[r] += h[r][k] * wv;
    }
#pragma unroll
    for (int r = 0; r < 8; r++) {
        float v = acc[r] + bt[c];
        v = (v >= 0.f) ? v : SLOPE * v;
        out[(size_t)(b0 + r) * EMB + c] = v + xgp[(size_t)(b0 + r) * EMB + c];
    }
}

extern "C" void kernel_launch(void* const* d_in, const int* in_sizes, int n_in,
                              void* d_out, int out_size, void* d_ws, size_t ws_size,
                              hipStream_t stream) {
    const float* xgp  = (const float*)d_in[0];
    const float* x    = (const float*)d_in[1];
    const int*   bind = (const int*)d_in[2];
    const float* Wm   = (const float*)d_in[3];
    const float* Wf   = (const float*)d_in[5];
    const float* bf   = (const float*)d_in[6];
    const float* Wtr  = (const float*)d_in[7];
    const float* bt   = (const float*)d_in[8];
    float* out = (float*)d_out;

    char* ws = (char*)d_ws;
    unsigned short* Wt2    = (unsigned short*)ws;                 // 128 KB (chunked)
    float*          dPart  = (float*)(ws + 131072);               // 8*512 f32 = 16 KB
    float*          xgPart = (float*)(ws + 131072 + 16384);       // 8*512*256 f32 = 4 MB

    hipLaunchKernelGGL(k_prep,  dim3(256 + 1028),              dim3(256),  0, stream,
                       Wf, Wt2, (float4*)xgPart, (float4*)dPart);
    hipLaunchKernelGGL(k_fused, dim3(NROWS / (64 * T_TILES)),  dim3(1024), 0, stream,
                       x, Wt2, Wm, bf, bind, dPart, xgPart);
    hipLaunchKernelGGL(k_out,   dim3(NB / 8),                  dim3(256),  0, stream,
                       xgPart, dPart, xgp, Wtr, bt, out);
}

// Round 16
// 144.511 us; speedup vs baseline: 2.7580x; 2.7580x over previous
//
#include <hip/hip_runtime.h>
#include <cstdint>
#include <cstddef>

#define NROWS 262144
#define EMB 256
#define NB 512
#define NCOPY 8
#define SLOPE 0.01f

typedef __attribute__((ext_vector_type(8))) short short8;
typedef __attribute__((ext_vector_type(4))) float f32x4;

__device__ __forceinline__ unsigned short f2bf(float f) {
    unsigned u = __float_as_uint(f);
    u += 0x7FFFu + ((u >> 16) & 1u);
    return (unsigned short)(u >> 16);
}

__device__ __forceinline__ short8 pack8(const float4& lo, const float4& hi) {
    short8 s;
    s[0] = (short)f2bf(lo.x); s[1] = (short)f2bf(lo.y);
    s[2] = (short)f2bf(lo.z); s[3] = (short)f2bf(lo.w);
    s[4] = (short)f2bf(hi.x); s[5] = (short)f2bf(hi.y);
    s[6] = (short)f2bf(hi.z); s[7] = (short)f2bf(hi.w);
    return s;
}

// async 16B global -> LDS (DMA) -- used for L2-resident B only
__device__ __forceinline__ void gld16u(unsigned short* l, const unsigned short* g) {
    __builtin_amdgcn_global_load_lds(
        (const __attribute__((address_space(1))) unsigned int*)g,
        (__attribute__((address_space(3))) unsigned int*)l, 16, 0, 0);
}

// ---------- prep (merged init): transpose W_feat + zero partial buffers ----------
__global__ __launch_bounds__(256) void k_prep(const float* __restrict__ Wf,
                                              unsigned short* __restrict__ Wt2,
                                              float4* __restrict__ xgPart4,
                                              float4* __restrict__ dPart4) {
    const int b = blockIdx.x, t = threadIdx.x;
    if (b < 256) {
        // W_feat[k=b][col=t] -> Wt2[k>>3][col][k&7]  (chunked: staging reads contiguous)
        float v = Wf[(size_t)b * EMB + t];
        Wt2[((size_t)(b >> 3) << 11) + (t << 3) + (b & 7)] = f2bf(v);
    } else {
        const int i = (b - 256) * 256 + t;
        if (i < NCOPY * NB * EMB / 4) xgPart4[i] = (float4){0.f, 0.f, 0.f, 0.f};
        else dPart4[i - NCOPY * NB * EMB / 4] = (float4){0.f, 0.f, 0.f, 0.f};
    }
}

// stage B K-step (32 k x 256 col bf16 = 16KB): 2 contiguous-slab DMA loads/thread
#define STAGE_B(B, KT) do {                                                       \
    _Pragma("unroll")                                                             \
    for (int q = 0; q < 2; q++) {                                                 \
        const int i_ = q * 512 + t;                                               \
        const int slab_ = i_ >> 8, off_ = i_ & 255;                               \
        gld16u(&bbuf[B][slab_ * 2048 + off_ * 8],                                 \
               Wt2 + (((size_t)((KT) >> 3) + slab_) << 11) + off_ * 8);           \
    }                                                                             \
} while (0)

// ---------- fused: gate + exp + bf16 MFMA feat GEMM + weighted segment reduce ----------
// 512 threads = 8 waves (wr 0..3 of 32 rows x wc 0..1 of 128 cols), tile 128x256,
// BK=32, 8 K-steps. R11's proven 2-barrier schedule; ONLY change: A is REG-STAGED
// (global_load_dwordx4 -> VGPR, depth-2, per-wave MLP) + ds_write_b128 into the
// same swizzled xbuf layout -- bypassing the HBM-fed global_load_lds capacity cap.
// B stays on the L2-fed DMA double-buffer. Shared vmcnt ledger, order pinned.
__global__ __launch_bounds__(512, 4) void k_fused(const float* __restrict__ x,
                                                  const unsigned short* __restrict__ Wt2,
                                                  const float* __restrict__ wm,
                                                  const float* __restrict__ bfeat,
                                                  const int* __restrict__ bind,
                                                  float* __restrict__ dPart,
                                                  float* __restrict__ xgPart) {
    __shared__ float          xbuf[2][128 * 32];   // A: 2 x 16 KB (chunk-XOR swizzled)
    __shared__ unsigned short bbuf[2][32 * 256];   // B: 2 x 16 KB, [k-chunk][col][8]
    __shared__ float wm_s[256];
    __shared__ float w_s[128];
    __shared__ float pxg[2][256];
    __shared__ float pden[2];
    __shared__ int   seg_s[128];
    __shared__ int   segid_s[8];
    __shared__ int   uni_s[8];

    const int t    = threadIdx.x;
    const int lane = t & 63;
    const int w    = t >> 6;
    const int wr   = w >> 1, wc = w & 1;   // wr: 32-row group 0..3, wc: 128-col half
    const int fr   = lane & 15;
    const int fg   = lane >> 4;
    const size_t r0 = (size_t)blockIdx.x * 128;
    const int cp   = blockIdx.x & (NCOPY - 1);

    if (t < 256) { wm_s[t] = wm[t]; pxg[0][t] = 0.f; pxg[1][t] = 0.f; }
    if (t < 128) seg_s[t] = bind[r0 + t];
    if (t < 2)   pden[t] = 0.f;

    // A reg-staging geometry: thread t handles chunk c0 of rows row0 and row0+64
    const int row0  = t >> 3, c0 = t & 7;
    const int wslot = c0 ^ (row0 & 7);               // same slot for row0 and row0+64
    const int wb0   = row0 * 32 + wslot * 4;
    const int wb1   = wb0 + 64 * 32;
    const float* xsrc0 = x + (r0 + row0) * EMB + c0 * 4;
    const float* xsrc1 = xsrc0 + (size_t)64 * EMB;

    // ---- prologue: A(0) regs, B(0) DMA, A(1) regs, write A(0) ----
    float4 aLo, aHi, nLo = {}, nHi = {};
    {
        float4 z0 = *reinterpret_cast<const float4*>(xsrc0);        // A(0)
        float4 z1 = *reinterpret_cast<const float4*>(xsrc1);
        __builtin_amdgcn_sched_barrier(0);
        STAGE_B(0, 0);                                              // B(0)
        __builtin_amdgcn_sched_barrier(0);
        aLo = *reinterpret_cast<const float4*>(xsrc0 + 32);         // A(1)
        aHi = *reinterpret_cast<const float4*>(xsrc1 + 32);
        __builtin_amdgcn_sched_barrier(0);
        asm volatile("s_waitcnt vmcnt(4)" ::: "memory");            // A(0) landed
        __builtin_amdgcn_sched_barrier(0);
        *reinterpret_cast<float4*>(&xbuf[0][wb0]) = z0;
        *reinterpret_cast<float4*>(&xbuf[0][wb1]) = z1;
    }

    f32x4 acc[2][8];
#pragma unroll
    for (int m = 0; m < 2; m++)
#pragma unroll
        for (int n = 0; n < 8; n++) acc[m][n] = (f32x4){0.f, 0.f, 0.f, 0.f};
    float gp0 = 0.f, gp1 = 0.f;

#pragma unroll
    for (int s = 0; s < 8; s++) {
        const int buf = s & 1;
        // (1) B DMA for step s+1
        if (s < 7) STAGE_B(buf ^ 1, (s + 1) * 32);
        __builtin_amdgcn_sched_barrier(0);
        // (2) A reg loads for step s+2 (deep per-wave MLP)
        if (s < 6) {
            nLo = *reinterpret_cast<const float4*>(xsrc0 + (s + 2) * 32);
            nHi = *reinterpret_cast<const float4*>(xsrc1 + (s + 2) * 32);
        }
        __builtin_amdgcn_sched_barrier(0);
        // (3) counted wait: retires B(s) + A-regs(s+1); B(s+1)/A(s+2) stay in flight
        if (s < 6)       asm volatile("s_waitcnt vmcnt(4)" ::: "memory");
        else if (s == 6) asm volatile("s_waitcnt vmcnt(2)" ::: "memory");
        else             asm volatile("s_waitcnt vmcnt(0)" ::: "memory");
        __builtin_amdgcn_sched_barrier(0);
        // (4) write A(s+1) into xbuf[buf^1] (read-released at barrier-2 of s-1)
        if (s < 7) {
            *reinterpret_cast<float4*>(&xbuf[buf ^ 1][wb0]) = aLo;
            *reinterpret_cast<float4*>(&xbuf[buf ^ 1][wb1]) = aHi;
        }
        // (5) own ds_writes drained -> barrier -> everyone's step-s data visible
        asm volatile("s_waitcnt lgkmcnt(0)" ::: "memory");
        __builtin_amdgcn_sched_barrier(0);
        __builtin_amdgcn_s_barrier();
        __builtin_amdgcn_sched_barrier(0);

        // ---- compute step s: pure LDS ----
        const float* xb = &xbuf[buf][0];
        const unsigned short* bb = &bbuf[buf][0];

        const float4 wa  = *reinterpret_cast<const float4*>(&wm_s[s * 32 + fg * 8]);
        const float4 wbv = *reinterpret_cast<const float4*>(&wm_s[s * 32 + fg * 8 + 4]);
        short8 a0, a1;
        {
            const int r  = wr * 32 + fr;
            const int sl = (fg * 2) ^ (r & 7);
            const float4 lo = *reinterpret_cast<const float4*>(&xb[r * 32 + sl * 4]);
            const float4 hi = *reinterpret_cast<const float4*>(&xb[r * 32 + (sl ^ 1) * 4]);
            gp0 += lo.x * wa.x + lo.y * wa.y + lo.z * wa.z + lo.w * wa.w
                 + hi.x * wbv.x + hi.y * wbv.y + hi.z * wbv.z + hi.w * wbv.w;
            a0 = pack8(lo, hi);
        }
        {
            const int r  = wr * 32 + 16 + fr;
            const int sl = (fg * 2) ^ (r & 7);
            const float4 lo = *reinterpret_cast<const float4*>(&xb[r * 32 + sl * 4]);
            const float4 hi = *reinterpret_cast<const float4*>(&xb[r * 32 + (sl ^ 1) * 4]);
            gp1 += lo.x * wa.x + lo.y * wa.y + lo.z * wa.z + lo.w * wa.w
                 + hi.x * wbv.x + hi.y * wbv.y + hi.z * wbv.z + hi.w * wbv.w;
            a1 = pack8(lo, hi);
        }
#pragma unroll
        for (int n = 0; n < 8; n++) {
            const short8 b = *reinterpret_cast<const short8*>(
                &bb[fg * 2048 + ((wc * 128 + n * 16 + fr) << 3)]);
            acc[0][n] = __builtin_amdgcn_mfma_f32_16x16x32_bf16(a0, b, acc[0][n], 0, 0, 0);
            acc[1][n] = __builtin_amdgcn_mfma_f32_16x16x32_bf16(a1, b, acc[1][n], 0, 0, 0);
        }

        // release buf[s&1] (LDS reads done) before iter s+1 overwrites it
        asm volatile("s_waitcnt lgkmcnt(0)" ::: "memory");
        __builtin_amdgcn_sched_barrier(0);
        __builtin_amdgcn_s_barrier();
        __builtin_amdgcn_sched_barrier(0);

        aLo = nLo; aHi = nHi;   // shift A-reg generation
    }

    // ---- gate -> e ----
    gp0 += __shfl_xor(gp0, 16, 64); gp0 += __shfl_xor(gp0, 32, 64);
    gp1 += __shfl_xor(gp1, 16, 64); gp1 += __shfl_xor(gp1, 32, 64);
    // exp(b_mask) cancels in the softmax -> dropped
    if (wc == 0 && lane < 16) {
        w_s[wr * 32 + lane]      = expf(gp0);
        w_s[wr * 32 + 16 + lane] = expf(gp1);
    }
    if (t < 8) {
        int s0 = seg_s[t * 16], ok = 1;
#pragma unroll
        for (int i = 1; i < 16; i++) ok &= (seg_s[t * 16 + i] == s0);
        segid_s[t] = s0;
        uni_s[t]   = ok;
    }
    __syncthreads();

    const int sid0 = seg_s[0];
    const int sid1 = seg_s[127];

    // ---- denom partials (LDS slots, global fallback for >2-segment tiles) ----
    if (t < 8) {
        if (uni_s[t]) {
            float s = 0.f;
#pragma unroll
            for (int i = 0; i < 16; i++) s += w_s[t * 16 + i];
            const int sid = segid_s[t];
            if (sid == sid0)      atomicAdd(&pden[0], s);
            else if (sid == sid1) atomicAdd(&pden[1], s);
            else atomicAdd(&dPart[cp * NB + sid], s);
        } else {
            for (int i = 0; i < 16; i++) {
                const int sd = seg_s[t * 16 + i];
                const float e = w_s[t * 16 + i];
                if (sd == sid0)      atomicAdd(&pden[0], e);
                else if (sd == sid1) atomicAdd(&pden[1], e);
                else atomicAdd(&dPart[cp * NB + sd], e);
            }
        }
    }

    // ---- epilogue: bias -> leaky -> *e -> segmented reduce -> LDS slots ----
#pragma unroll
    for (int m = 0; m < 2; m++) {
        const int g    = wr * 2 + m;
        const int uni  = uni_s[g];
        const int sid  = segid_s[g];
        const int rowb = wr * 32 + m * 16;
#pragma unroll
        for (int n = 0; n < 8; n++) {
            const int col = wc * 128 + n * 16 + fr;
            const float bia = bfeat[col];
            float vr[4];
#pragma unroll
            for (int r2 = 0; r2 < 4; r2++) {
                const int row = rowb + fg * 4 + r2;
                float v = acc[m][n][r2] + bia;
                v = (v >= 0.f) ? v : SLOPE * v;
                vr[r2] = v * w_s[row];
            }
            if (uni) {
                float s = vr[0] + vr[1] + vr[2] + vr[3];
                s += __shfl_xor(s, 16, 64);
                s += __shfl_xor(s, 32, 64);
                if (fg == 0) {
                    if (sid == sid0)      atomicAdd(&pxg[0][col], s);
                    else if (sid == sid1) atomicAdd(&pxg[1][col], s);
                    else atomicAdd(&xgPart[((size_t)(cp * NB + sid) << 8) + col], s);
                }
            } else {
#pragma unroll
                for (int r2 = 0; r2 < 4; r2++) {
                    const int sd = seg_s[rowb + fg * 4 + r2];
                    if (sd == sid0)      atomicAdd(&pxg[0][col], vr[r2]);
                    else if (sd == sid1) atomicAdd(&pxg[1][col], vr[r2]);
                    else atomicAdd(&xgPart[((size_t)(cp * NB + sd) << 8) + col], vr[r2]);
                }
            }
        }
    }
    __syncthreads();

    // ---- flush block partials into XCD-striped copies ----
    if (t < 256) {
        atomicAdd(&xgPart[((size_t)(cp * NB + sid0) << 8) + t], pxg[0][t]);
    } else if (sid1 != sid0) {
        atomicAdd(&xgPart[((size_t)(cp * NB + sid1) << 8) + (t - 256)], pxg[1][t - 256]);
    }
    if (t == 0) atomicAdd(&dPart[cp * NB + sid0], pden[0]);
    if (t == 1 && sid1 != sid0) atomicAdd(&dPart[cp * NB + sid1], pden[1]);
}

// ---------- out = leaky_relu([xg/denom, xg_prev] @ W_t + b_t) + xg_prev ----------
__global__ __launch_bounds__(256) void k_out(const float* __restrict__ xgPart,
                                             const float* __restrict__ dPart,
                                             const float* __restrict__ xgp,
                                             const float* __restrict__ Wtr,
                                             const float* __restrict__ bt,
                                             float* __restrict__ out) {
    __shared__ float h[8][512];
    const int c  = threadIdx.x;
    const int b0 = blockIdx.x * 8;
#pragma unroll
    for (int r = 0; r < 8; r++) {
        const int b = b0 + r;
        float den = 0.f, s = 0.f;
#pragma unroll
        for (int cpy = 0; cpy < NCOPY; cpy++) {
            den += dPart[cpy * NB + b];
            s   += xgPart[((size_t)(cpy * NB + b) << 8) + c];
        }
        h[r][c]       = s / fmaxf(den, 1e-16f);
        h[r][EMB + c] = xgp[(size_t)b * EMB + c];
    }
    __syncthreads();
    float acc[8] = {0.f, 0.f, 0.f, 0.f, 0.f, 0.f, 0.f, 0.f};
    for (int k = 0; k < 2 * EMB; k++) {
        float wv = Wtr[(size_t)k * EMB + c];
#pragma unroll
        for (int r = 0; r < 8; r++) acc[r] += h[r][k] * wv;
    }
#pragma unroll
    for (int r = 0; r < 8; r++) {
        float v = acc[r] + bt[c];
        v = (v >= 0.f) ? v : SLOPE * v;
        out[(size_t)(b0 + r) * EMB + c] = v + xgp[(size_t)(b0 + r) * EMB + c];
    }
}

extern "C" void kernel_launch(void* const* d_in, const int* in_sizes, int n_in,
                              void* d_out, int out_size, void* d_ws, size_t ws_size,
                              hipStream_t stream) {
    const float* xgp  = (const float*)d_in[0];
    const float* x    = (const float*)d_in[1];
    const int*   bind = (const int*)d_in[2];
    const float* Wm   = (const float*)d_in[3];
    const float* Wf   = (const float*)d_in[5];
    const float* bf   = (const float*)d_in[6];
    const float* Wtr  = (const float*)d_in[7];
    const float* bt   = (const float*)d_in[8];
    float* out = (float*)d_out;

    char* ws = (char*)d_ws;
    unsigned short* Wt2    = (unsigned short*)ws;                 // 128 KB (chunked)
    float*          dPart  = (float*)(ws + 131072);               // 8*512 f32 = 16 KB
    float*          xgPart = (float*)(ws + 131072 + 16384);       // 8*512*256 f32 = 4 MB

    hipLaunchKernelGGL(k_prep,  dim3(256 + 1028), dim3(256), 0, stream,
                       Wf, Wt2, (float4*)xgPart, (float4*)dPart);
    hipLaunchKernelGGL(k_fused, dim3(NROWS / 128), dim3(512), 0, stream,
                       x, Wt2, Wm, bf, bind, dPart, xgPart);
    hipLaunchKernelGGL(k_out,   dim3(NB / 8),     dim3(256), 0, stream,
                       xgPart, dPart, xgp, Wtr, bt, out);
}

// Round 17
// 143.460 us; speedup vs baseline: 2.7782x; 1.0073x over previous
//
#include <hip/hip_runtime.h>
#include <cstdint>
#include <cstddef>

#define NROWS 262144
#define EMB 256
#define NB 512
#define NCOPY 8
#define SLOPE 0.01f

typedef __attribute__((ext_vector_type(8))) short short8;
typedef __attribute__((ext_vector_type(4))) float f32x4;

__device__ __forceinline__ unsigned short f2bf(float f) {
    unsigned u = __float_as_uint(f);
    u += 0x7FFFu + ((u >> 16) & 1u);
    return (unsigned short)(u >> 16);
}

__device__ __forceinline__ short8 pack8(const float4& lo, const float4& hi) {
    short8 s;
    s[0] = (short)f2bf(lo.x); s[1] = (short)f2bf(lo.y);
    s[2] = (short)f2bf(lo.z); s[3] = (short)f2bf(lo.w);
    s[4] = (short)f2bf(hi.x); s[5] = (short)f2bf(hi.y);
    s[6] = (short)f2bf(hi.z); s[7] = (short)f2bf(hi.w);
    return s;
}

// async 16B global -> LDS (DMA, no VGPR round trip)
__device__ __forceinline__ void gld16f(float* l, const float* g) {
    __builtin_amdgcn_global_load_lds(
        (const __attribute__((address_space(1))) unsigned int*)g,
        (__attribute__((address_space(3))) unsigned int*)l, 16, 0, 0);
}
__device__ __forceinline__ void gld16u(unsigned short* l, const unsigned short* g) {
    __builtin_amdgcn_global_load_lds(
        (const __attribute__((address_space(1))) unsigned int*)g,
        (__attribute__((address_space(3))) unsigned int*)l, 16, 0, 0);
}

// ---------- prep (merged init): transpose W_feat + zero partial buffers ----------
__global__ __launch_bounds__(256) void k_prep(const float* __restrict__ Wf,
                                              unsigned short* __restrict__ Wt2,
                                              float4* __restrict__ xgPart4,
                                              float4* __restrict__ dPart4) {
    const int b = blockIdx.x, t = threadIdx.x;
    if (b < 256) {
        // W_feat[k=b][col=t] -> Wt2[k>>3][col][k&7]  (chunked: staging reads contiguous)
        float v = Wf[(size_t)b * EMB + t];
        Wt2[((size_t)(b >> 3) << 11) + (t << 3) + (b & 7)] = f2bf(v);
    } else {
        const int i = (b - 256) * 256 + t;
        if (i < NCOPY * NB * EMB / 4) xgPart4[i] = (float4){0.f, 0.f, 0.f, 0.f};
        else dPart4[i - NCOPY * NB * EMB / 4] = (float4){0.f, 0.f, 0.f, 0.f};
    }
}

// stage K-step (32 k): A 256x32 f32 (row-chunk XOR swizzled src, 2 loads/thread),
// B 32x256 bf16 chunked (1 contiguous-slab load/thread). 3 DMA/thread total.
#define STAGE(B, KT) do {                                                         \
    _Pragma("unroll")                                                             \
    for (int q = 0; q < 2; q++) {                                                 \
        const int i_ = q * 1024 + t;                                              \
        const int row_ = i_ >> 3, c_ = i_ & 7;                                    \
        const int cs_ = c_ ^ (row_ & 7);                                          \
        gld16f(&xbuf[B][i_ * 4], x + ((r0 + row_) << 8) + (KT) + (cs_ << 2));     \
    }                                                                             \
    {                                                                             \
        const int slab_ = t >> 8, off_ = t & 255;                                 \
        gld16u(&bbuf[B][slab_ * 2048 + off_ * 8],                                 \
               Wt2 + (((size_t)((KT) >> 3) + slab_) << 11) + off_ * 8);           \
    }                                                                             \
} while (0)

// ---------- fused: gate + exp + bf16 MFMA feat GEMM + weighted segment reduce ----------
// 1024 threads = 16 waves (wr 0..7 of 32 rows x wc 0..1 of 128 cols), tile 256x256,
// BK=32, 8 K-steps. R11's proven 2-barrier counted-vmcnt schedule, tile scaled 2x:
// per-step fixed costs amortized over 2x output, B re-stage traffic halved.
// LDS ~104 KB -> 1 block/CU = 16 waves/CU.
__global__ __launch_bounds__(1024, 4) void k_fused(const float* __restrict__ x,
                                                   const unsigned short* __restrict__ Wt2,
                                                   const float* __restrict__ wm,
                                                   const float* __restrict__ bfeat,
                                                   const int* __restrict__ bind,
                                                   float* __restrict__ dPart,
                                                   float* __restrict__ xgPart) {
    __shared__ float          xbuf[2][256 * 32];   // A: 2 x 32 KB (chunk-XOR swizzled)
    __shared__ unsigned short bbuf[2][32 * 256];   // B: 2 x 16 KB, [k-chunk][col][8]
    __shared__ float wm_s[256];
    __shared__ float w_s[256];
    __shared__ float pxg[2][256];
    __shared__ float pden[2];
    __shared__ int   seg_s[256];
    __shared__ int   segid_s[16];
    __shared__ int   uni_s[16];

    const int t    = threadIdx.x;
    const int lane = t & 63;
    const int w    = t >> 6;
    const int wr   = w >> 1, wc = w & 1;   // wr: 32-row group 0..7, wc: 128-col half
    const int fr   = lane & 15;
    const int fg   = lane >> 4;
    const size_t r0 = (size_t)blockIdx.x * 256;
    const int cp   = blockIdx.x & (NCOPY - 1);

    if (t < 256) {
        wm_s[t] = wm[t];
        pxg[0][t] = 0.f;
        pxg[1][t] = 0.f;
        seg_s[t] = bind[r0 + t];
    }
    if (t < 2) pden[t] = 0.f;

    // prologue: stage step 0
    STAGE(0, 0);

    f32x4 acc[2][8];
#pragma unroll
    for (int m = 0; m < 2; m++)
#pragma unroll
        for (int n = 0; n < 8; n++) acc[m][n] = (f32x4){0.f, 0.f, 0.f, 0.f};
    float gp0 = 0.f, gp1 = 0.f;

#pragma unroll
    for (int s = 0; s < 8; s++) {
        const int buf = s & 1;
        if (s < 7) STAGE(buf ^ 1, (s + 1) * 32);   // issue next step's 3 loads
        // counted wait: retire step-s's 3 loads; step-(s+1)'s stay in flight.
        // s==0 also drains lgkm so smem init (wm_s/seg_s/pxg) is visible to all.
        if (s == 0)     asm volatile("s_waitcnt vmcnt(3) lgkmcnt(0)" ::: "memory");
        else if (s < 7) asm volatile("s_waitcnt vmcnt(3)" ::: "memory");
        else            asm volatile("s_waitcnt vmcnt(0)" ::: "memory");
        __builtin_amdgcn_sched_barrier(0);
        __builtin_amdgcn_s_barrier();      // all waves' step-s data landed
        __builtin_amdgcn_sched_barrier(0);

        // ---- compute step s: pure LDS ----
        const float* xb = &xbuf[buf][0];
        const unsigned short* bb = &bbuf[buf][0];

        const float4 wa  = *reinterpret_cast<const float4*>(&wm_s[s * 32 + fg * 8]);
        const float4 wbv = *reinterpret_cast<const float4*>(&wm_s[s * 32 + fg * 8 + 4]);
        short8 a0, a1;
        {
            const int r  = wr * 32 + fr;
            const int sl = (fg * 2) ^ (r & 7);
            const float4 lo = *reinterpret_cast<const float4*>(&xb[r * 32 + sl * 4]);
            const float4 hi = *reinterpret_cast<const float4*>(&xb[r * 32 + (sl ^ 1) * 4]);
            gp0 += lo.x * wa.x + lo.y * wa.y + lo.z * wa.z + lo.w * wa.w
                 + hi.x * wbv.x + hi.y * wbv.y + hi.z * wbv.z + hi.w * wbv.w;
            a0 = pack8(lo, hi);
        }
        {
            const int r  = wr * 32 + 16 + fr;
            const int sl = (fg * 2) ^ (r & 7);
            const float4 lo = *reinterpret_cast<const float4*>(&xb[r * 32 + sl * 4]);
            const float4 hi = *reinterpret_cast<const float4*>(&xb[r * 32 + (sl ^ 1) * 4]);
            gp1 += lo.x * wa.x + lo.y * wa.y + lo.z * wa.z + lo.w * wa.w
                 + hi.x * wbv.x + hi.y * wbv.y + hi.z * wbv.z + hi.w * wbv.w;
            a1 = pack8(lo, hi);
        }
#pragma unroll
        for (int n = 0; n < 8; n++) {
            const short8 b = *reinterpret_cast<const short8*>(
                &bb[fg * 2048 + ((wc * 128 + n * 16 + fr) << 3)]);
            acc[0][n] = __builtin_amdgcn_mfma_f32_16x16x32_bf16(a0, b, acc[0][n], 0, 0, 0);
            acc[1][n] = __builtin_amdgcn_mfma_f32_16x16x32_bf16(a1, b, acc[1][n], 0, 0, 0);
        }

        // release buf[s&1]: all waves' ds_reads done before iter s+1 re-stages it
        asm volatile("s_waitcnt lgkmcnt(0)" ::: "memory");
        __builtin_amdgcn_sched_barrier(0);
        __builtin_amdgcn_s_barrier();
        __builtin_amdgcn_sched_barrier(0);
    }

    // ---- gate -> e ----
    gp0 += __shfl_xor(gp0, 16, 64); gp0 += __shfl_xor(gp0, 32, 64);
    gp1 += __shfl_xor(gp1, 16, 64); gp1 += __shfl_xor(gp1, 32, 64);
    // exp(b_mask) cancels in the softmax -> dropped
    if (wc == 0 && lane < 16) {
        w_s[wr * 32 + lane]      = expf(gp0);
        w_s[wr * 32 + 16 + lane] = expf(gp1);
    }
    if (t < 16) {
        int s0 = seg_s[t * 16], ok = 1;
#pragma unroll
        for (int i = 1; i < 16; i++) ok &= (seg_s[t * 16 + i] == s0);
        segid_s[t] = s0;
        uni_s[t]   = ok;
    }
    __syncthreads();

    const int sid0 = seg_s[0];
    const int sid1 = seg_s[255];

    // ---- denom partials (LDS slots, global fallback for middle segments) ----
    if (t < 16) {
        if (uni_s[t]) {
            float s = 0.f;
#pragma unroll
            for (int i = 0; i < 16; i++) s += w_s[t * 16 + i];
            const int sid = segid_s[t];
            if (sid == sid0)      atomicAdd(&pden[0], s);
            else if (sid == sid1) atomicAdd(&pden[1], s);
            else atomicAdd(&dPart[cp * NB + sid], s);
        } else {
            for (int i = 0; i < 16; i++) {
                const int sd = seg_s[t * 16 + i];
                const float e = w_s[t * 16 + i];
                if (sd == sid0)      atomicAdd(&pden[0], e);
                else if (sd == sid1) atomicAdd(&pden[1], e);
                else atomicAdd(&dPart[cp * NB + sd], e);
            }
        }
    }

    // ---- epilogue: bias -> leaky -> *e -> segmented reduce -> LDS slots ----
#pragma unroll
    for (int m = 0; m < 2; m++) {
        const int g    = wr * 2 + m;
        const int uni  = uni_s[g];
        const int sid  = segid_s[g];
        const int rowb = wr * 32 + m * 16;
#pragma unroll
        for (int n = 0; n < 8; n++) {
            const int col = wc * 128 + n * 16 + fr;
            const float bia = bfeat[col];
            float vr[4];
#pragma unroll
            for (int r2 = 0; r2 < 4; r2++) {
                const int row = rowb + fg * 4 + r2;
                float v = acc[m][n][r2] + bia;
                v = (v >= 0.f) ? v : SLOPE * v;
                vr[r2] = v * w_s[row];
            }
            if (uni) {
                float s = vr[0] + vr[1] + vr[2] + vr[3];
                s += __shfl_xor(s, 16, 64);
                s += __shfl_xor(s, 32, 64);
                if (fg == 0) {
                    if (sid == sid0)      atomicAdd(&pxg[0][col], s);
                    else if (sid == sid1) atomicAdd(&pxg[1][col], s);
                    else atomicAdd(&xgPart[((size_t)(cp * NB + sid) << 8) + col], s);
                }
            } else {
#pragma unroll
                for (int r2 = 0; r2 < 4; r2++) {
                    const int sd = seg_s[rowb + fg * 4 + r2];
                    if (sd == sid0)      atomicAdd(&pxg[0][col], vr[r2]);
                    else if (sd == sid1) atomicAdd(&pxg[1][col], vr[r2]);
                    else atomicAdd(&xgPart[((size_t)(cp * NB + sd) << 8) + col], vr[r2]);
                }
            }
        }
    }
    __syncthreads();

    // ---- flush block partials into XCD-striped copies ----
    if (t < 256) {
        atomicAdd(&xgPart[((size_t)(cp * NB + sid0) << 8) + t], pxg[0][t]);
    } else if (t < 512) {
        if (sid1 != sid0)
            atomicAdd(&xgPart[((size_t)(cp * NB + sid1) << 8) + (t - 256)], pxg[1][t - 256]);
    } else if (t == 512) {
        atomicAdd(&dPart[cp * NB + sid0], pden[0]);
    } else if (t == 513) {
        if (sid1 != sid0) atomicAdd(&dPart[cp * NB + sid1], pden[1]);
    }
}

// ---------- out = leaky_relu([xg/denom, xg_prev] @ W_t + b_t) + xg_prev ----------
__global__ __launch_bounds__(256) void k_out(const float* __restrict__ xgPart,
                                             const float* __restrict__ dPart,
                                             const float* __restrict__ xgp,
                                             const float* __restrict__ Wtr,
                                             const float* __restrict__ bt,
                                             float* __restrict__ out) {
    __shared__ float h[8][512];
    const int c  = threadIdx.x;
    const int b0 = blockIdx.x * 8;
#pragma unroll
    for (int r = 0; r < 8; r++) {
        const int b = b0 + r;
        float den = 0.f, s = 0.f;
#pragma unroll
        for (int cpy = 0; cpy < NCOPY; cpy++) {
            den += dPart[cpy * NB + b];
            s   += xgPart[((size_t)(cpy * NB + b) << 8) + c];
        }
        h[r][c]       = s / fmaxf(den, 1e-16f);
        h[r][EMB + c] = xgp[(size_t)b * EMB + c];
    }
    __syncthreads();
    float acc[8] = {0.f, 0.f, 0.f, 0.f, 0.f, 0.f, 0.f, 0.f};
    for (int k = 0; k < 2 * EMB; k++) {
        float wv = Wtr[(size_t)k * EMB + c];
#pragma unroll
        for (int r = 0; r < 8; r++) acc[r] += h[r][k] * wv;
    }
#pragma unroll
    for (int r = 0; r < 8; r++) {
        float v = acc[r] + bt[c];
        v = (v >= 0.f) ? v : SLOPE * v;
        out[(size_t)(b0 + r) * EMB + c] = v + xgp[(size_t)(b0 + r) * EMB + c];
    }
}

extern "C" void kernel_launch(void* const* d_in, const int* in_sizes, int n_in,
                              void* d_out, int out_size, void* d_ws, size_t ws_size,
                              hipStream_t stream) {
    const float* xgp  = (const float*)d_in[0];
    const float* x    = (const float*)d_in[1];
    const int*   bind = (const int*)d_in[2];
    const float* Wm   = (const float*)d_in[3];
    const float* Wf   = (const float*)d_in[5];
    const float* bf   = (const float*)d_in[6];
    const float* Wtr  = (const float*)d_in[7];
    const float* bt   = (const float*)d_in[8];
    float* out = (float*)d_out;

    char* ws = (char*)d_ws;
    unsigned short* Wt2    = (unsigned short*)ws;                 // 128 KB (chunked)
    float*          dPart  = (float*)(ws + 131072);               // 8*512 f32 = 16 KB
    float*          xgPart = (float*)(ws + 131072 + 16384);       // 8*512*256 f32 = 4 MB

    hipLaunchKernelGGL(k_prep,  dim3(256 + 1028), dim3(256),  0, stream,
                       Wf, Wt2, (float4*)xgPart, (float4*)dPart);
    hipLaunchKernelGGL(k_fused, dim3(NROWS / 256), dim3(1024), 0, stream,
                       x, Wt2, Wm, bf, bind, dPart, xgPart);
    hipLaunchKernelGGL(k_out,   dim3(NB / 8),     dim3(256),  0, stream,
                       xgPart, dPart, xgp, Wtr, bt, out);
}

// Round 18
// 136.298 us; speedup vs baseline: 2.9241x; 1.0525x over previous
//
#include <hip/hip_runtime.h>
#include <cstdint>
#include <cstddef>

#define NROWS 262144
#define EMB 256
#define NB 512
#define NCOPY 8
#define SLOPE 0.01f

typedef __attribute__((ext_vector_type(8))) short short8;
typedef __attribute__((ext_vector_type(4))) float f32x4;

__device__ __forceinline__ unsigned short f2bf(float f) {
    unsigned u = __float_as_uint(f);
    u += 0x7FFFu + ((u >> 16) & 1u);
    return (unsigned short)(u >> 16);
}

__device__ __forceinline__ short8 pack8(const float4& lo, const float4& hi) {
    short8 s;
    s[0] = (short)f2bf(lo.x); s[1] = (short)f2bf(lo.y);
    s[2] = (short)f2bf(lo.z); s[3] = (short)f2bf(lo.w);
    s[4] = (short)f2bf(hi.x); s[5] = (short)f2bf(hi.y);
    s[6] = (short)f2bf(hi.z); s[7] = (short)f2bf(hi.w);
    return s;
}

// async 16B global -> LDS (DMA, no VGPR round trip)
__device__ __forceinline__ void gld16f(float* l, const float* g) {
    __builtin_amdgcn_global_load_lds(
        (const __attribute__((address_space(1))) unsigned int*)g,
        (__attribute__((address_space(3))) unsigned int*)l, 16, 0, 0);
}
__device__ __forceinline__ void gld16u(unsigned short* l, const unsigned short* g) {
    __builtin_amdgcn_global_load_lds(
        (const __attribute__((address_space(1))) unsigned int*)g,
        (__attribute__((address_space(3))) unsigned int*)l, 16, 0, 0);
}

// ---------- prep (merged init): transpose W_feat + zero partial buffers ----------
__global__ __launch_bounds__(256) void k_prep(const float* __restrict__ Wf,
                                              unsigned short* __restrict__ Wt2,
                                              float4* __restrict__ xgPart4,
                                              float4* __restrict__ dPart4) {
    const int b = blockIdx.x, t = threadIdx.x;
    if (b < 256) {
        // W_feat[k=b][col=t] -> Wt2[k>>3][col][k&7]  (chunked: staging reads contiguous)
        float v = Wf[(size_t)b * EMB + t];
        Wt2[((size_t)(b >> 3) << 11) + (t << 3) + (b & 7)] = f2bf(v);
    } else {
        const int i = (b - 256) * 256 + t;
        if (i < NCOPY * NB * EMB / 4) xgPart4[i] = (float4){0.f, 0.f, 0.f, 0.f};
        else dPart4[i - NCOPY * NB * EMB / 4] = (float4){0.f, 0.f, 0.f, 0.f};
    }
}

// stage K-step (32 k): A 128x32 f32 (row-chunk XOR swizzled src),
// B 32x256 bf16 chunked (contiguous slabs). 4 DMA instructions per thread.
#define STAGE(B, KT) do {                                                         \
    _Pragma("unroll")                                                             \
    for (int q = 0; q < 2; q++) {                                                 \
        const int i_ = q * 512 + t;                                               \
        const int row_ = i_ >> 3, c_ = i_ & 7;                                    \
        const int cs_ = c_ ^ (row_ & 7);                                          \
        gld16f(&xbuf[B][i_ * 4], x + ((r0 + row_) << 8) + (KT) + (cs_ << 2));     \
    }                                                                             \
    _Pragma("unroll")                                                             \
    for (int q = 0; q < 2; q++) {                                                 \
        const int i_ = q * 512 + t;                                               \
        const int slab_ = i_ >> 8, off_ = i_ & 255;                               \
        gld16u(&bbuf[B][slab_ * 2048 + off_ * 8],                                 \
               Wt2 + (((size_t)((KT) >> 3) + slab_) << 11) + off_ * 8);           \
    }                                                                             \
} while (0)

// ---------- fused: gate + exp + bf16 MFMA feat GEMM + weighted segment reduce ----------
// R11's best-measured configuration, verbatim: 512 threads = 8 waves
// (wr 0..3 of 32 rows x wc 0..1 of 128 cols), tile 128 x 256, BK=32, 8 K-steps,
// A+B LDS double-buffered DMA with counted vmcnt(4). 2 blocks/CU = 16 waves/CU.
__global__ __launch_bounds__(512, 4) void k_fused(const float* __restrict__ x,
                                                  const unsigned short* __restrict__ Wt2,
                                                  const float* __restrict__ wm,
                                                  const float* __restrict__ bfeat,
                                                  const int* __restrict__ bind,
                                                  float* __restrict__ dPart,
                                                  float* __restrict__ xgPart) {
    __shared__ float          xbuf[2][128 * 32];   // A: 2 x 16 KB
    __shared__ unsigned short bbuf[2][32 * 256];   // B: 2 x 16 KB, [k-chunk][col][8]
    __shared__ float wm_s[256];
    __shared__ float w_s[128];
    __shared__ float pxg[2][256];
    __shared__ float pden[2];
    __shared__ int   seg_s[128];
    __shared__ int   segid_s[8];
    __shared__ int   uni_s[8];

    const int t    = threadIdx.x;
    const int lane = t & 63;
    const int w    = t >> 6;
    const int wr   = w >> 1, wc = w & 1;   // wr: 32-row group 0..3, wc: 128-col half
    const int fr   = lane & 15;
    const int fg   = lane >> 4;
    const size_t r0 = (size_t)blockIdx.x * 128;
    const int cp   = blockIdx.x & (NCOPY - 1);

    if (t < 256) { wm_s[t] = wm[t]; pxg[0][t] = 0.f; pxg[1][t] = 0.f; }
    if (t < 128) seg_s[t] = bind[r0 + t];
    if (t < 2)   pden[t] = 0.f;

    // prologue: stage step 0
    STAGE(0, 0);

    f32x4 acc[2][8];
#pragma unroll
    for (int m = 0; m < 2; m++)
#pragma unroll
        for (int n = 0; n < 8; n++) acc[m][n] = (f32x4){0.f, 0.f, 0.f, 0.f};
    float gp0 = 0.f, gp1 = 0.f;

#pragma unroll
    for (int s = 0; s < 8; s++) {
        const int buf = s & 1;
        if (s < 7) STAGE(buf ^ 1, (s + 1) * 32);   // issue next step's 4 loads
        // counted wait: retire step-s's 4 loads; step-(s+1)'s stay in flight.
        // s==0 also drains lgkm so smem init (wm_s/seg_s/pxg) is visible to all.
        if (s == 0)     asm volatile("s_waitcnt vmcnt(4) lgkmcnt(0)" ::: "memory");
        else if (s < 7) asm volatile("s_waitcnt vmcnt(4)" ::: "memory");
        else            asm volatile("s_waitcnt vmcnt(0)" ::: "memory");
        __builtin_amdgcn_sched_barrier(0);
        __builtin_amdgcn_s_barrier();      // all waves' step-s data landed
        __builtin_amdgcn_sched_barrier(0);

        // ---- compute step s: pure LDS ----
        const float* xb = &xbuf[buf][0];
        const unsigned short* bb = &bbuf[buf][0];

        const float4 wa  = *reinterpret_cast<const float4*>(&wm_s[s * 32 + fg * 8]);
        const float4 wbv = *reinterpret_cast<const float4*>(&wm_s[s * 32 + fg * 8 + 4]);
        short8 a0, a1;
        {
            const int r  = wr * 32 + fr;
            const int sl = (fg * 2) ^ (r & 7);
            const float4 lo = *reinterpret_cast<const float4*>(&xb[r * 32 + sl * 4]);
            const float4 hi = *reinterpret_cast<const float4*>(&xb[r * 32 + (sl ^ 1) * 4]);
            gp0 += lo.x * wa.x + lo.y * wa.y + lo.z * wa.z + lo.w * wa.w
                 + hi.x * wbv.x + hi.y * wbv.y + hi.z * wbv.z + hi.w * wbv.w;
            a0 = pack8(lo, hi);
        }
        {
            const int r  = wr * 32 + 16 + fr;
            const int sl = (fg * 2) ^ (r & 7);
            const float4 lo = *reinterpret_cast<const float4*>(&xb[r * 32 + sl * 4]);
            const float4 hi = *reinterpret_cast<const float4*>(&xb[r * 32 + (sl ^ 1) * 4]);
            gp1 += lo.x * wa.x + lo.y * wa.y + lo.z * wa.z + lo.w * wa.w
                 + hi.x * wbv.x + hi.y * wbv.y + hi.z * wbv.z + hi.w * wbv.w;
            a1 = pack8(lo, hi);
        }
#pragma unroll
        for (int n = 0; n < 8; n++) {
            const short8 b = *reinterpret_cast<const short8*>(
                &bb[fg * 2048 + ((wc * 128 + n * 16 + fr) << 3)]);
            acc[0][n] = __builtin_amdgcn_mfma_f32_16x16x32_bf16(a0, b, acc[0][n], 0, 0, 0);
            acc[1][n] = __builtin_amdgcn_mfma_f32_16x16x32_bf16(a1, b, acc[1][n], 0, 0, 0);
        }

        // release buf[s&1]: all waves' ds_reads done before iter s+1 re-stages it
        asm volatile("s_waitcnt lgkmcnt(0)" ::: "memory");
        __builtin_amdgcn_sched_barrier(0);
        __builtin_amdgcn_s_barrier();
        __builtin_amdgcn_sched_barrier(0);
    }

    // ---- gate -> e ----
    gp0 += __shfl_xor(gp0, 16, 64); gp0 += __shfl_xor(gp0, 32, 64);
    gp1 += __shfl_xor(gp1, 16, 64); gp1 += __shfl_xor(gp1, 32, 64);
    // exp(b_mask) cancels in the softmax -> dropped
    if (wc == 0 && lane < 16) {
        w_s[wr * 32 + lane]      = expf(gp0);
        w_s[wr * 32 + 16 + lane] = expf(gp1);
    }
    if (t < 8) {
        int s0 = seg_s[t * 16], ok = 1;
#pragma unroll
        for (int i = 1; i < 16; i++) ok &= (seg_s[t * 16 + i] == s0);
        segid_s[t] = s0;
        uni_s[t]   = ok;
    }
    __syncthreads();

    const int sid0 = seg_s[0];
    const int sid1 = seg_s[127];

    // ---- denom partials (LDS slots, global fallback for middle segments) ----
    if (t < 8) {
        if (uni_s[t]) {
            float s = 0.f;
#pragma unroll
            for (int i = 0; i < 16; i++) s += w_s[t * 16 + i];
            const int sid = segid_s[t];
            if (sid == sid0)      atomicAdd(&pden[0], s);
            else if (sid == sid1) atomicAdd(&pden[1], s);
            else atomicAdd(&dPart[cp * NB + sid], s);
        } else {
            for (int i = 0; i < 16; i++) {
                const int sd = seg_s[t * 16 + i];
                const float e = w_s[t * 16 + i];
                if (sd == sid0)      atomicAdd(&pden[0], e);
                else if (sd == sid1) atomicAdd(&pden[1], e);
                else atomicAdd(&dPart[cp * NB + sd], e);
            }
        }
    }

    // ---- epilogue: bias -> leaky -> *e -> segmented reduce -> LDS slots ----
#pragma unroll
    for (int m = 0; m < 2; m++) {
        const int g    = wr * 2 + m;
        const int uni  = uni_s[g];
        const int sid  = segid_s[g];
        const int rowb = wr * 32 + m * 16;
#pragma unroll
        for (int n = 0; n < 8; n++) {
            const int col = wc * 128 + n * 16 + fr;
            const float bia = bfeat[col];
            float vr[4];
#pragma unroll
            for (int r2 = 0; r2 < 4; r2++) {
                const int row = rowb + fg * 4 + r2;
                float v = acc[m][n][r2] + bia;
                v = (v >= 0.f) ? v : SLOPE * v;
                vr[r2] = v * w_s[row];
            }
            if (uni) {
                float s = vr[0] + vr[1] + vr[2] + vr[3];
                s += __shfl_xor(s, 16, 64);
                s += __shfl_xor(s, 32, 64);
                if (fg == 0) {
                    if (sid == sid0)      atomicAdd(&pxg[0][col], s);
                    else if (sid == sid1) atomicAdd(&pxg[1][col], s);
                    else atomicAdd(&xgPart[((size_t)(cp * NB + sid) << 8) + col], s);
                }
            } else {
#pragma unroll
                for (int r2 = 0; r2 < 4; r2++) {
                    const int sd = seg_s[rowb + fg * 4 + r2];
                    if (sd == sid0)      atomicAdd(&pxg[0][col], vr[r2]);
                    else if (sd == sid1) atomicAdd(&pxg[1][col], vr[r2]);
                    else atomicAdd(&xgPart[((size_t)(cp * NB + sd) << 8) + col], vr[r2]);
                }
            }
        }
    }
    __syncthreads();

    // ---- flush block partials into XCD-striped copies ----
    if (t < 256) {
        atomicAdd(&xgPart[((size_t)(cp * NB + sid0) << 8) + t], pxg[0][t]);
    } else if (sid1 != sid0) {
        atomicAdd(&xgPart[((size_t)(cp * NB + sid1) << 8) + (t - 256)], pxg[1][t - 256]);
    }
    if (t == 0) atomicAdd(&dPart[cp * NB + sid0], pden[0]);
    if (t == 1 && sid1 != sid0) atomicAdd(&dPart[cp * NB + sid1], pden[1]);
}

// ---------- out = leaky_relu([xg/denom, xg_prev] @ W_t + b_t) + xg_prev ----------
// One block per output row b (512 blocks, 2 blocks/CU) -- was 64 blocks (0.25/CU).
__global__ __launch_bounds__(256) void k_out(const float* __restrict__ xgPart,
                                             const float* __restrict__ dPart,
                                             const float* __restrict__ xgp,
                                             const float* __restrict__ Wtr,
                                             const float* __restrict__ bt,
                                             float* __restrict__ out) {
    __shared__ float h[512];
    const int c = threadIdx.x;
    const int b = blockIdx.x;

    float den = 0.f, s = 0.f;
#pragma unroll
    for (int cpy = 0; cpy < NCOPY; cpy++) {
        den += dPart[cpy * NB + b];
        s   += xgPart[((size_t)(cpy * NB + b) << 8) + c];
    }
    const float xp = xgp[(size_t)b * EMB + c];
    h[c]       = s / fmaxf(den, 1e-16f);
    h[EMB + c] = xp;
    __syncthreads();

    float acc = 0.f;
#pragma unroll 8
    for (int k = 0; k < 2 * EMB; k++) {
        acc += h[k] * Wtr[(size_t)k * EMB + c];
    }
    float v = acc + bt[c];
    v = (v >= 0.f) ? v : SLOPE * v;
    out[(size_t)b * EMB + c] = v + xp;
}

extern "C" void kernel_launch(void* const* d_in, const int* in_sizes, int n_in,
                              void* d_out, int out_size, void* d_ws, size_t ws_size,
                              hipStream_t stream) {
    const float* xgp  = (const float*)d_in[0];
    const float* x    = (const float*)d_in[1];
    const int*   bind = (const int*)d_in[2];
    const float* Wm   = (const float*)d_in[3];
    const float* Wf   = (const float*)d_in[5];
    const float* bf   = (const float*)d_in[6];
    const float* Wtr  = (const float*)d_in[7];
    const float* bt   = (const float*)d_in[8];
    float* out = (float*)d_out;

    char* ws = (char*)d_ws;
    unsigned short* Wt2    = (unsigned short*)ws;                 // 128 KB (chunked)
    float*          dPart  = (float*)(ws + 131072);               // 8*512 f32 = 16 KB
    float*          xgPart = (float*)(ws + 131072 + 16384);       // 8*512*256 f32 = 4 MB

    hipLaunchKernelGGL(k_prep,  dim3(256 + 1028),  dim3(256), 0, stream,
                       Wf, Wt2, (float4*)xgPart, (float4*)dPart);
    hipLaunchKernelGGL(k_fused, dim3(NROWS / 128), dim3(512), 0, stream,
                       x, Wt2, Wm, bf, bind, dPart, xgPart);
    hipLaunchKernelGGL(k_out,   dim3(NB),          dim3(256), 0, stream,
                       xgPart, dPart, xgp, Wtr, bt, out);
}

// Round 19
// 134.745 us; speedup vs baseline: 2.9579x; 1.0115x over previous
//
#include <hip/hip_runtime.h>
#include <cstdint>
#include <cstddef>

#define NROWS 262144
#define EMB 256
#define NB 512
#define NCOPY 4
#define SLOPE 0.01f

typedef __attribute__((ext_vector_type(8))) short short8;
typedef __attribute__((ext_vector_type(4))) float f32x4;

__device__ __forceinline__ unsigned short f2bf(float f) {
    unsigned u = __float_as_uint(f);
    u += 0x7FFFu + ((u >> 16) & 1u);
    return (unsigned short)(u >> 16);
}

__device__ __forceinline__ short8 pack8(const float4& lo, const float4& hi) {
    short8 s;
    s[0] = (short)f2bf(lo.x); s[1] = (short)f2bf(lo.y);
    s[2] = (short)f2bf(lo.z); s[3] = (short)f2bf(lo.w);
    s[4] = (short)f2bf(hi.x); s[5] = (short)f2bf(hi.y);
    s[6] = (short)f2bf(hi.z); s[7] = (short)f2bf(hi.w);
    return s;
}

// async 16B global -> LDS (DMA, no VGPR round trip)
__device__ __forceinline__ void gld16f(float* l, const float* g) {
    __builtin_amdgcn_global_load_lds(
        (const __attribute__((address_space(1))) unsigned int*)g,
        (__attribute__((address_space(3))) unsigned int*)l, 16, 0, 0);
}
__device__ __forceinline__ void gld16u(unsigned short* l, const unsigned short* g) {
    __builtin_amdgcn_global_load_lds(
        (const __attribute__((address_space(1))) unsigned int*)g,
        (__attribute__((address_space(3))) unsigned int*)l, 16, 0, 0);
}

// ---------- prep (merged init): transpose W_feat + zero partial buffers ----------
// blocks 0..255: Wt2 transpose; blocks 256..769: zero xgPart (2 MB) + dPart (8 KB)
__global__ __launch_bounds__(256) void k_prep(const float* __restrict__ Wf,
                                              unsigned short* __restrict__ Wt2,
                                              float4* __restrict__ xgPart4,
                                              float4* __restrict__ dPart4) {
    const int b = blockIdx.x, t = threadIdx.x;
    if (b < 256) {
        // W_feat[k=b][col=t] -> Wt2[k>>3][col][k&7]  (chunked: staging reads contiguous)
        float v = Wf[(size_t)b * EMB + t];
        Wt2[((size_t)(b >> 3) << 11) + (t << 3) + (b & 7)] = f2bf(v);
    } else {
        const int i = (b - 256) * 256 + t;
        if (i < NCOPY * NB * EMB / 4) xgPart4[i] = (float4){0.f, 0.f, 0.f, 0.f};
        else dPart4[i - NCOPY * NB * EMB / 4] = (float4){0.f, 0.f, 0.f, 0.f};
    }
}

// stage K-step (32 k): A 128x32 f32 (row-chunk XOR swizzled src),
// B 32x256 bf16 chunked (contiguous slabs). 4 DMA instructions per thread.
#define STAGE(B, KT) do {                                                         \
    _Pragma("unroll")                                                             \
    for (int q = 0; q < 2; q++) {                                                 \
        const int i_ = q * 512 + t;                                               \
        const int row_ = i_ >> 3, c_ = i_ & 7;                                    \
        const int cs_ = c_ ^ (row_ & 7);                                          \
        gld16f(&xbuf[B][i_ * 4], x + ((r0 + row_) << 8) + (KT) + (cs_ << 2));     \
    }                                                                             \
    _Pragma("unroll")                                                             \
    for (int q = 0; q < 2; q++) {                                                 \
        const int i_ = q * 512 + t;                                               \
        const int slab_ = i_ >> 8, off_ = i_ & 255;                               \
        gld16u(&bbuf[B][slab_ * 2048 + off_ * 8],                                 \
               Wt2 + (((size_t)((KT) >> 3) + slab_) << 11) + off_ * 8);           \
    }                                                                             \
} while (0)

// ---------- fused: gate + exp + bf16 MFMA feat GEMM + weighted segment reduce ----------
// Best-measured configuration (R11/R18), verbatim: 512 threads = 8 waves
// (wr 0..3 of 32 rows x wc 0..1 of 128 cols), tile 128 x 256, BK=32, 8 K-steps,
// A+B LDS double-buffered DMA with counted vmcnt(4). 2 blocks/CU = 16 waves/CU.
__global__ __launch_bounds__(512, 4) void k_fused(const float* __restrict__ x,
                                                  const unsigned short* __restrict__ Wt2,
                                                  const float* __restrict__ wm,
                                                  const float* __restrict__ bfeat,
                                                  const int* __restrict__ bind,
                                                  float* __restrict__ dPart,
                                                  float* __restrict__ xgPart) {
    __shared__ float          xbuf[2][128 * 32];   // A: 2 x 16 KB
    __shared__ unsigned short bbuf[2][32 * 256];   // B: 2 x 16 KB, [k-chunk][col][8]
    __shared__ float wm_s[256];
    __shared__ float w_s[128];
    __shared__ float pxg[2][256];
    __shared__ float pden[2];
    __shared__ int   seg_s[128];
    __shared__ int   segid_s[8];
    __shared__ int   uni_s[8];

    const int t    = threadIdx.x;
    const int lane = t & 63;
    const int w    = t >> 6;
    const int wr   = w >> 1, wc = w & 1;   // wr: 32-row group 0..3, wc: 128-col half
    const int fr   = lane & 15;
    const int fg   = lane >> 4;
    const size_t r0 = (size_t)blockIdx.x * 128;
    const int cp   = blockIdx.x & (NCOPY - 1);

    if (t < 256) { wm_s[t] = wm[t]; pxg[0][t] = 0.f; pxg[1][t] = 0.f; }
    if (t < 128) seg_s[t] = bind[r0 + t];
    if (t < 2)   pden[t] = 0.f;

    // prologue: stage step 0
    STAGE(0, 0);

    f32x4 acc[2][8];
#pragma unroll
    for (int m = 0; m < 2; m++)
#pragma unroll
        for (int n = 0; n < 8; n++) acc[m][n] = (f32x4){0.f, 0.f, 0.f, 0.f};
    float gp0 = 0.f, gp1 = 0.f;

#pragma unroll
    for (int s = 0; s < 8; s++) {
        const int buf = s & 1;
        if (s < 7) STAGE(buf ^ 1, (s + 1) * 32);   // issue next step's 4 loads
        // counted wait: retire step-s's 4 loads; step-(s+1)'s stay in flight.
        // s==0 also drains lgkm so smem init (wm_s/seg_s/pxg) is visible to all.
        if (s == 0)     asm volatile("s_waitcnt vmcnt(4) lgkmcnt(0)" ::: "memory");
        else if (s < 7) asm volatile("s_waitcnt vmcnt(4)" ::: "memory");
        else            asm volatile("s_waitcnt vmcnt(0)" ::: "memory");
        __builtin_amdgcn_sched_barrier(0);
        __builtin_amdgcn_s_barrier();      // all waves' step-s data landed
        __builtin_amdgcn_sched_barrier(0);

        // ---- compute step s: pure LDS ----
        const float* xb = &xbuf[buf][0];
        const unsigned short* bb = &bbuf[buf][0];

        const float4 wa  = *reinterpret_cast<const float4*>(&wm_s[s * 32 + fg * 8]);
        const float4 wbv = *reinterpret_cast<const float4*>(&wm_s[s * 32 + fg * 8 + 4]);
        short8 a0, a1;
        {
            const int r  = wr * 32 + fr;
            const int sl = (fg * 2) ^ (r & 7);
            const float4 lo = *reinterpret_cast<const float4*>(&xb[r * 32 + sl * 4]);
            const float4 hi = *reinterpret_cast<const float4*>(&xb[r * 32 + (sl ^ 1) * 4]);
            gp0 += lo.x * wa.x + lo.y * wa.y + lo.z * wa.z + lo.w * wa.w
                 + hi.x * wbv.x + hi.y * wbv.y + hi.z * wbv.z + hi.w * wbv.w;
            a0 = pack8(lo, hi);
        }
        {
            const int r  = wr * 32 + 16 + fr;
            const int sl = (fg * 2) ^ (r & 7);
            const float4 lo = *reinterpret_cast<const float4*>(&xb[r * 32 + sl * 4]);
            const float4 hi = *reinterpret_cast<const float4*>(&xb[r * 32 + (sl ^ 1) * 4]);
            gp1 += lo.x * wa.x + lo.y * wa.y + lo.z * wa.z + lo.w * wa.w
                 + hi.x * wbv.x + hi.y * wbv.y + hi.z * wbv.z + hi.w * wbv.w;
            a1 = pack8(lo, hi);
        }
#pragma unroll
        for (int n = 0; n < 8; n++) {
            const short8 b = *reinterpret_cast<const short8*>(
                &bb[fg * 2048 + ((wc * 128 + n * 16 + fr) << 3)]);
            acc[0][n] = __builtin_amdgcn_mfma_f32_16x16x32_bf16(a0, b, acc[0][n], 0, 0, 0);
            acc[1][n] = __builtin_amdgcn_mfma_f32_16x16x32_bf16(a1, b, acc[1][n], 0, 0, 0);
        }

        // release buf[s&1]: all waves' ds_reads done before iter s+1 re-stages it
        asm volatile("s_waitcnt lgkmcnt(0)" ::: "memory");
        __builtin_amdgcn_sched_barrier(0);
        __builtin_amdgcn_s_barrier();
        __builtin_amdgcn_sched_barrier(0);
    }

    // ---- gate -> e ----
    gp0 += __shfl_xor(gp0, 16, 64); gp0 += __shfl_xor(gp0, 32, 64);
    gp1 += __shfl_xor(gp1, 16, 64); gp1 += __shfl_xor(gp1, 32, 64);
    // exp(b_mask) cancels in the softmax -> dropped
    if (wc == 0 && lane < 16) {
        w_s[wr * 32 + lane]      = expf(gp0);
        w_s[wr * 32 + 16 + lane] = expf(gp1);
    }
    if (t < 8) {
        int s0 = seg_s[t * 16], ok = 1;
#pragma unroll
        for (int i = 1; i < 16; i++) ok &= (seg_s[t * 16 + i] == s0);
        segid_s[t] = s0;
        uni_s[t]   = ok;
    }
    __syncthreads();

    const int sid0 = seg_s[0];
    const int sid1 = seg_s[127];

    // ---- denom partials (LDS slots, global fallback for middle segments) ----
    if (t < 8) {
        if (uni_s[t]) {
            float s = 0.f;
#pragma unroll
            for (int i = 0; i < 16; i++) s += w_s[t * 16 + i];
            const int sid = segid_s[t];
            if (sid == sid0)      atomicAdd(&pden[0], s);
            else if (sid == sid1) atomicAdd(&pden[1], s);
            else atomicAdd(&dPart[cp * NB + sid], s);
        } else {
            for (int i = 0; i < 16; i++) {
                const int sd = seg_s[t * 16 + i];
                const float e = w_s[t * 16 + i];
                if (sd == sid0)      atomicAdd(&pden[0], e);
                else if (sd == sid1) atomicAdd(&pden[1], e);
                else atomicAdd(&dPart[cp * NB + sd], e);
            }
        }
    }

    // ---- epilogue: bias -> leaky -> *e -> segmented reduce -> LDS slots ----
#pragma unroll
    for (int m = 0; m < 2; m++) {
        const int g    = wr * 2 + m;
        const int uni  = uni_s[g];
        const int sid  = segid_s[g];
        const int rowb = wr * 32 + m * 16;
#pragma unroll
        for (int n = 0; n < 8; n++) {
            const int col = wc * 128 + n * 16 + fr;
            const float bia = bfeat[col];
            float vr[4];
#pragma unroll
            for (int r2 = 0; r2 < 4; r2++) {
                const int row = rowb + fg * 4 + r2;
                float v = acc[m][n][r2] + bia;
                v = (v >= 0.f) ? v : SLOPE * v;
                vr[r2] = v * w_s[row];
            }
            if (uni) {
                float s = vr[0] + vr[1] + vr[2] + vr[3];
                s += __shfl_xor(s, 16, 64);
                s += __shfl_xor(s, 32, 64);
                if (fg == 0) {
                    if (sid == sid0)      atomicAdd(&pxg[0][col], s);
                    else if (sid == sid1) atomicAdd(&pxg[1][col], s);
                    else atomicAdd(&xgPart[((size_t)(cp * NB + sid) << 8) + col], s);
                }
            } else {
#pragma unroll
                for (int r2 = 0; r2 < 4; r2++) {
                    const int sd = seg_s[rowb + fg * 4 + r2];
                    if (sd == sid0)      atomicAdd(&pxg[0][col], vr[r2]);
                    else if (sd == sid1) atomicAdd(&pxg[1][col], vr[r2]);
                    else atomicAdd(&xgPart[((size_t)(cp * NB + sd) << 8) + col], vr[r2]);
                }
            }
        }
    }
    __syncthreads();

    // ---- flush block partials into XCD-striped copies ----
    if (t < 256) {
        atomicAdd(&xgPart[((size_t)(cp * NB + sid0) << 8) + t], pxg[0][t]);
    } else if (sid1 != sid0) {
        atomicAdd(&xgPart[((size_t)(cp * NB + sid1) << 8) + (t - 256)], pxg[1][t - 256]);
    }
    if (t == 0) atomicAdd(&dPart[cp * NB + sid0], pden[0]);
    if (t == 1 && sid1 != sid0) atomicAdd(&dPart[cp * NB + sid1], pden[1]);
}

// ---------- out = leaky_relu([xg/denom, xg_prev] @ W_t + b_t) + xg_prev ----------
// One block per output row b (512 blocks, 2 blocks/CU).
__global__ __launch_bounds__(256) void k_out(const float* __restrict__ xgPart,
                                             const float* __restrict__ dPart,
                                             const float* __restrict__ xgp,
                                             const float* __restrict__ Wtr,
                                             const float* __restrict__ bt,
                                             float* __restrict__ out) {
    __shared__ float h[512];
    const int c = threadIdx.x;
    const int b = blockIdx.x;

    float den = 0.f, s = 0.f;
#pragma unroll
    for (int cpy = 0; cpy < NCOPY; cpy++) {
        den += dPart[cpy * NB + b];
        s   += xgPart[((size_t)(cpy * NB + b) << 8) + c];
    }
    const float xp = xgp[(size_t)b * EMB + c];
    h[c]       = s / fmaxf(den, 1e-16f);
    h[EMB + c] = xp;
    __syncthreads();

    float acc = 0.f;
#pragma unroll 8
    for (int k = 0; k < 2 * EMB; k++) {
        acc += h[k] * Wtr[(size_t)k * EMB + c];
    }
    float v = acc + bt[c];
    v = (v >= 0.f) ? v : SLOPE * v;
    out[(size_t)b * EMB + c] = v + xp;
}

extern "C" void kernel_launch(void* const* d_in, const int* in_sizes, int n_in,
                              void* d_out, int out_size, void* d_ws, size_t ws_size,
                              hipStream_t stream) {
    const float* xgp  = (const float*)d_in[0];
    const float* x    = (const float*)d_in[1];
    const int*   bind = (const int*)d_in[2];
    const float* Wm   = (const float*)d_in[3];
    const float* Wf   = (const float*)d_in[5];
    const float* bf   = (const float*)d_in[6];
    const float* Wtr  = (const float*)d_in[7];
    const float* bt   = (const float*)d_in[8];
    float* out = (float*)d_out;

    char* ws = (char*)d_ws;
    unsigned short* Wt2    = (unsigned short*)ws;                 // 128 KB (chunked)
    float*          dPart  = (float*)(ws + 131072);               // 4*512 f32 = 8 KB
    float*          xgPart = (float*)(ws + 131072 + 16384);       // 4*512*256 f32 = 2 MB

    // zero-fill work: 4*512*256/4 + 4*512/4 = 131584 float4s -> 514 blocks
    hipLaunchKernelGGL(k_prep,  dim3(256 + 514),   dim3(256), 0, stream,
                       Wf, Wt2, (float4*)xgPart, (float4*)dPart);
    hipLaunchKernelGGL(k_fused, dim3(NROWS / 128), dim3(512), 0, stream,
                       x, Wt2, Wm, bf, bind, dPart, xgPart);
    hipLaunchKernelGGL(k_out,   dim3(NB),          dim3(256), 0, stream,
                       xgPart, dPart, xgp, Wtr, bt, out);
}